// Round 4
// baseline (306.324 us; speedup 1.0000x reference)
//
#include <hip/hip_runtime.h>

#define NPTS 16384
#define KNN 16
#define HID 64
#define NCLS 10

#define WPB 4              // waves per block (knn_sel)
#define QPB 8              // queries per block (knn_sel)
#define SCAP 128           // per-query survivor capacity (block-shared LDS list)
#define GRPQ 32            // candidate groups per wave quarter (knn_sel)
#define NITER 16           // iters per scan of a quarter (2 groups per iter)
#define NGRP (NPTS / 128)  // 128 total pair-groups
#define TQW 4              // queries per wave (knn_tau)
#define TPAD 576           // pm2t prefetch pad (float4), max overrun 512

typedef float v2f __attribute__((ext_vector_type(2)));

// packed distance: D = {d(c0), d(c1)} = Qx*X + Qy*Y + Qz*Z + W  (3 pk_fma)
__device__ __forceinline__ v2f pdist(v2f Qx, v2f Qy, v2f Qz, v2f X, v2f Y, v2f Z, v2f W) {
    return __builtin_elementwise_fma(Qx, X,
            __builtin_elementwise_fma(Qy, Y,
             __builtin_elementwise_fma(Qz, Z, W)));
}

// scalar twin (rescan path) — identical op order => bit-exact vs packed halves
__device__ __forceinline__ float distm2(float qx, float qy, float qz, float4 c) {
    return fmaf(qx, c.x, fmaf(qy, c.y, fmaf(qz, c.z, c.w)));
}

// wave-uniform float -> SGPR
__device__ __forceinline__ float __frfl(float x) {
    return __int_as_float(__builtin_amdgcn_readfirstlane(__float_as_int(x)));
}

// monotone float->u32, packed with index: ascending u64 order == (d asc, j asc)
__device__ __forceinline__ unsigned long long dkey(float v, int j) {
    unsigned u = __float_as_uint(v);
    u = (u & 0x80000000u) ? ~u : (u | 0x80000000u);
    return ((unsigned long long)u << 32) | (unsigned)j;
}

__device__ __forceinline__ unsigned long long shfl_xor_u64(unsigned long long x, int m) {
    unsigned hi = (unsigned)__shfl_xor((int)(x >> 32), m, 64);
    unsigned lo = (unsigned)__shfl_xor((int)(x & 0xffffffffu), m, 64);
    return ((unsigned long long)hi << 32) | lo;
}

// exact wave-wide top-16 (rescan slow path only)
__device__ __forceinline__ void wave_top16_16(unsigned long long (&key)[16], int lane,
                                              int q, int* __restrict__ idx) {
    int outj = 0x7fffffff;
    for (int r = 0; r < 16; ++r) {
        unsigned long long gm = key[0];
#pragma unroll
        for (int s = 1; s < 16; ++s) gm = key[s] < gm ? key[s] : gm;
#pragma unroll
        for (int st = 1; st < 64; st <<= 1) {
            unsigned long long o = shfl_xor_u64(gm, st);
            gm = o < gm ? o : gm;
        }
        if (lane == r) outj = (int)(gm & 0xffffffffu);
#pragma unroll
        for (int s = 0; s < 16; ++s)
            if (key[s] == gm) key[s] = ~0ull;
    }
    if (lane < 16) idx[q * KNN + lane] = outj;
}

// pos (N,3) -> pos4 (x,y,z,|p|^2), pm2 (-2x,-2y,-2z,|p|^2) [rescan path],
// pm2t pair-transposed: group g (64 pairs): [g*128+l]=(x0,x1,y0,y1) of pair g*64+l,
//                                           [g*128+64+l]=(z0,z1,w0,w1)
__global__ void prep_kernel(const float* __restrict__ pos, float4* __restrict__ pos4,
                            float4* __restrict__ pm2, float4* __restrict__ pm2t) {
    int i = blockIdx.x * 256 + threadIdx.x;
    if (i < NPTS) {
        float x = pos[3 * i], y = pos[3 * i + 1], z = pos[3 * i + 2];
        float sq = fmaf(x, x, fmaf(y, y, z * z));
        pos4[i] = make_float4(x, y, z, sq);
        pm2[i] = make_float4(-2.f * x, -2.f * y, -2.f * z, sq);
    }
    if (i < NPTS / 2) {
        int p = i;                       // pair p = candidates 2p, 2p+1
        float x0 = pos[6 * p],     y0 = pos[6 * p + 1], z0 = pos[6 * p + 2];
        float x1 = pos[6 * p + 3], y1 = pos[6 * p + 4], z1 = pos[6 * p + 5];
        float w0 = fmaf(x0, x0, fmaf(y0, y0, z0 * z0));
        float w1 = fmaf(x1, x1, fmaf(y1, y1, z1 * z1));
        int g = p >> 6, l = p & 63;
        pm2t[g * 128 + l]      = make_float4(-2.f * x0, -2.f * x1, -2.f * y0, -2.f * y1);
        pm2t[g * 128 + 64 + l] = make_float4(-2.f * z0, -2.f * z1, w0, w1);
    }
}

// knn_tau: BARRIER-FREE, LDS-FREE tau. One wave owns TQW=4 queries and scans
// all N candidates (packed pairs), producing exact stream-minima tau:
// tau = max over 16 streams (candidate-lane mod 16) of the stream minimum.
// Guarantees >=16 points with d <= tau (each stream contributes one).
__global__ __launch_bounds__(256) void knn_tau_kernel(const float4* __restrict__ pos4,
                                                      const float4* __restrict__ pm2t,
                                                      float* __restrict__ tqg) {
    int lane = threadIdx.x & 63;
    int w = threadIdx.x >> 6;
    int q0 = (blockIdx.x * 4 + w) * TQW;
    v2f Qx[TQW], Qy[TQW], Qz[TQW];
#pragma unroll
    for (int i = 0; i < TQW; ++i) {
        float4 t4 = pos4[q0 + i];          // wave-uniform
        float ax = __frfl(t4.x), ay = __frfl(t4.y), az = __frfl(t4.z);
        Qx[i] = (v2f){ax, ax}; Qy[i] = (v2f){ay, ay}; Qz[i] = (v2f){az, az};
    }
    const float4* pt = pm2t + lane;
    float mn[TQW];
#pragma unroll
    for (int i = 0; i < TQW; ++i) mn[i] = INFINITY;
    {
        float4 aXY0 = pt[0],   aZW0 = pt[64],  aXY1 = pt[128], aZW1 = pt[192];
        float4 bXY0 = pt[256], bZW0 = pt[320], bXY1 = pt[384], bZW1 = pt[448];
        int off = 512;
#pragma unroll 2
        for (int t = 0; t < NGRP / 2; ++t) {       // 64 iters, 2 groups each
            v2f X0 = {aXY0.x, aXY0.y}, Y0 = {aXY0.z, aXY0.w};
            v2f Z0 = {aZW0.x, aZW0.y}, W0 = {aZW0.z, aZW0.w};
            v2f X1 = {aXY1.x, aXY1.y}, Y1 = {aXY1.z, aXY1.w};
            v2f Z1 = {aZW1.x, aZW1.y}, W1 = {aZW1.z, aZW1.w};
#pragma unroll
            for (int i = 0; i < TQW; ++i) {
                v2f D0 = pdist(Qx[i], Qy[i], Qz[i], X0, Y0, Z0, W0);
                v2f D1 = pdist(Qx[i], Qy[i], Qz[i], X1, Y1, Z1, W1);
                mn[i] = fminf(mn[i], fminf(D0.x, D0.y));   // v_min3
                mn[i] = fminf(mn[i], fminf(D1.x, D1.y));   // v_min3
            }
            aXY0 = bXY0; aZW0 = bZW0; aXY1 = bXY1; aZW1 = bZW1;
            bXY0 = pt[off]; bZW0 = pt[off + 64];
            bXY1 = pt[off + 128]; bZW1 = pt[off + 192];
            off += 256;   // pad keeps trailing prefetches in-bounds
        }
    }
#pragma unroll
    for (int i = 0; i < TQW; ++i) {
        float m = mn[i];
        m = fminf(m, __shfl_xor(m, 16, 64));   // lane now holds stream-min(lane&15)
        m = fminf(m, __shfl_xor(m, 32, 64));
        m = fmaxf(m, __shfl_xor(m, 1, 64));    // max over the 16 stream minima
        m = fmaxf(m, __shfl_xor(m, 2, 64));
        m = fmaxf(m, __shfl_xor(m, 4, 64));
        m = fmaxf(m, __shfl_xor(m, 8, 64));
        if (lane == 0) tqg[q0 + i] = m;
    }
}

// knn_sel: tau-filtered push + rank-select extraction. Block = 4 waves sharing
// 8 queries; wave w scans its quarter (candidate-split). One real barrier.
__global__ __launch_bounds__(256) void knn_sel_kernel(const float4* __restrict__ pos4,
                                                      const float4* __restrict__ pm2,
                                                      const float4* __restrict__ pm2t,
                                                      const float* __restrict__ tqg,
                                                      int* __restrict__ idx) {
    __shared__ unsigned long long keys[QPB][SCAP];   // 8KB
    __shared__ int knt[QPB];
    int tid = threadIdx.x;
    int lane = tid & 63;
    int w = tid >> 6;
    int qb = blockIdx.x * QPB;
    v2f Qx[QPB], Qy[QPB], Qz[QPB];
    float tq[QPB];
#pragma unroll
    for (int i = 0; i < QPB; ++i) {
        float4 t4 = pos4[qb + i];          // wave-uniform (needed for rescan)
        float ax = __frfl(t4.x), ay = __frfl(t4.y), az = __frfl(t4.z);
        Qx[i] = (v2f){ax, ax}; Qy[i] = (v2f){ay, ay}; Qz[i] = (v2f){az, az};
        tq[i] = __frfl(tqg[qb + i]);
    }
    if (tid < QPB) knt[tid] = 0;
    __syncthreads();   // knt visible (also covers nothing else: no pre-work)

    const float4* pt = pm2t + (size_t)w * (GRPQ * 128) + lane;
    {
        float4 aXY0 = pt[0],   aZW0 = pt[64],  aXY1 = pt[128], aZW1 = pt[192];
        float4 bXY0 = pt[256], bZW0 = pt[320], bXY1 = pt[384], bZW1 = pt[448];
        int off = 512;
        int j00 = 2 * (w * (GRPQ * 64) + lane);   // candidate idx of slot0, iter 0
#pragma unroll 2
        for (int t = 0; t < NITER; ++t) {
            v2f X0 = {aXY0.x, aXY0.y}, Y0 = {aXY0.z, aXY0.w};
            v2f Z0 = {aZW0.x, aZW0.y}, W0 = {aZW0.z, aZW0.w};
            v2f X1 = {aXY1.x, aXY1.y}, Y1 = {aXY1.z, aXY1.w};
            v2f Z1 = {aZW1.x, aZW1.y}, W1 = {aZW1.z, aZW1.w};
            int j10 = j00 + 128;
#pragma unroll
            for (int i = 0; i < QPB; ++i) {
                v2f D0 = pdist(Qx[i], Qy[i], Qz[i], X0, Y0, Z0, W0);
                v2f D1 = pdist(Qx[i], Qy[i], Qz[i], X1, Y1, Z1, W1);
                float m01 = fminf(fminf(D0.x, D0.y), fminf(D1.x, D1.y));
                if (__any(m01 <= tq[i])) {             // vccz skip most iters
                    if (D0.x <= tq[i]) { int s = atomicAdd(&knt[i], 1); if (s < SCAP) keys[i][s] = dkey(D0.x, j00); }
                    if (D0.y <= tq[i]) { int s = atomicAdd(&knt[i], 1); if (s < SCAP) keys[i][s] = dkey(D0.y, j00 + 1); }
                    if (D1.x <= tq[i]) { int s = atomicAdd(&knt[i], 1); if (s < SCAP) keys[i][s] = dkey(D1.x, j10); }
                    if (D1.y <= tq[i]) { int s = atomicAdd(&knt[i], 1); if (s < SCAP) keys[i][s] = dkey(D1.y, j10 + 1); }
                }
            }
            aXY0 = bXY0; aZW0 = bZW0; aXY1 = bXY1; aZW1 = bZW1;
            bXY0 = pt[off]; bZW0 = pt[off + 64];
            bXY1 = pt[off + 128]; bZW1 = pt[off + 192];
            off += 256;
            j00 += 256;
        }
    }
    __syncthreads();   // all pushes visible

    // ---- Extraction: wave w handles queries 2w, 2w+1; 8-wide rank loop ----
#pragma unroll
    for (int e = 0; e < 2; ++e) {
        int qi = w * 2 + e;
        int q = qb + qi;
        int ntot = knt[qi];
        if (ntot >= KNN && ntot <= SCAP) {
            unsigned long long k0 = (lane < ntot) ? keys[qi][lane] : ~0ull;
            unsigned long long k1 = (lane + 64 < ntot) ? keys[qi][lane + 64] : ~0ull;
            int r0 = 0, r1 = 0;
            int t = 0;
            for (; t + 8 <= ntot; t += 8) {             // 8 independent ds_reads
                unsigned long long a0 = keys[qi][t + 0], a1 = keys[qi][t + 1];
                unsigned long long a2 = keys[qi][t + 2], a3 = keys[qi][t + 3];
                unsigned long long a4 = keys[qi][t + 4], a5 = keys[qi][t + 5];
                unsigned long long a6 = keys[qi][t + 6], a7 = keys[qi][t + 7];
                r0 += (int)(a0 < k0) + (int)(a1 < k0) + (int)(a2 < k0) + (int)(a3 < k0)
                    + (int)(a4 < k0) + (int)(a5 < k0) + (int)(a6 < k0) + (int)(a7 < k0);
                r1 += (int)(a0 < k1) + (int)(a1 < k1) + (int)(a2 < k1) + (int)(a3 < k1)
                    + (int)(a4 < k1) + (int)(a5 < k1) + (int)(a6 < k1) + (int)(a7 < k1);
            }
            for (; t < ntot; ++t) {
                unsigned long long k = keys[qi][t];
                r0 += (int)(k < k0);
                r1 += (int)(k < k1);
            }
            if (lane < ntot && r0 < KNN) idx[q * KNN + r0] = (int)(k0 & 0xffffffffu);
            if (lane + 64 < ntot && r1 < KNN) idx[q * KNN + r1] = (int)(k1 & 0xffffffffu);
        } else {
            // rescan: overflow -> tau-filtered (tau >= d16 guaranteed by ntot>SCAP>=16);
            // underflow (defensive, can't trigger with exact tau) -> unfiltered top-16
            float tqq = (ntot > SCAP) ? tq[qi] : INFINITY;
            float ax = Qx[qi].x, ay = Qy[qi].x, az = Qz[qi].x;
            unsigned long long key[16];
#pragma unroll
            for (int u = 0; u < 16; ++u) key[u] = ~0ull;
            for (int j = lane; j < NPTS; j += 64) {
                float v = distm2(ax, ay, az, pm2[j]);
                unsigned long long k = dkey(v, j);
                if (v <= tqq && k < key[15]) {
#pragma unroll
                    for (int s = 0; s < 16; ++s) {
                        unsigned long long a = k < key[s] ? k : key[s];
                        unsigned long long b = k < key[s] ? key[s] : k;
                        key[s] = a;
                        k = b;
                    }
                }
            }
            wave_top16_16(key, lane, q, idx);
        }
    }
}

// FUSED EdgeConv1 + ec2_pre (both pointwise in p; h1 never touches global).
__global__ __launch_bounds__(256) void ec12_kernel(const float4* __restrict__ pos4,
                                                   const int* __restrict__ idx,
                                                   const float* __restrict__ W1,
                                                   const float* __restrict__ b1,
                                                   const float* __restrict__ W2,
                                                   const float* __restrict__ b2,
                                                   float* __restrict__ C2,
                                                   float* __restrict__ Y2) {
    __shared__ float h1s[16][64];    // 4KB, [w*4+i][t], wave-private slices
    int t = threadIdx.x & 63;
    int w = threadIdx.x >> 6;
    int pb = blockIdx.x * 16 + w * 4;
    float w0 = W1[0 * HID + t], w1 = W1[1 * HID + t], w2 = W1[2 * HID + t];
    float v0 = W1[3 * HID + t], v1 = W1[4 * HID + t], v2 = W1[5 * HID + t];
    float bt1 = b1[t];
#pragma unroll
    for (int i = 0; i < 4; ++i) {
        int p = pb + i;
        float4 xi = pos4[p];
        float C = bt1 + xi.x * (w0 - v0) + xi.y * (w1 - v1) + xi.z * (w2 - v2);
        const int4* ip = (const int4*)(idx + (size_t)p * KNN);
        int4 n0 = ip[0], n1 = ip[1], n2 = ip[2], n3 = ip[3];   // 4 parallel loads
        int jj[16] = {n0.x, n0.y, n0.z, n0.w, n1.x, n1.y, n1.z, n1.w,
                      n2.x, n2.y, n2.z, n2.w, n3.x, n3.y, n3.z, n3.w};
        float m = -INFINITY;
#pragma unroll
        for (int k = 0; k < KNN; ++k) {
            float4 xj = pos4[jj[k]];      // 16 mutually-independent uniform loads
            m = fmaxf(m, fmaf(xj.x, v0, fmaf(xj.y, v1, xj.z * v2)));
        }
        h1s[w * 4 + i][t] = fmaxf(C + m, 0.f);
    }
    __syncthreads();
    float aa[4] = {0.f, 0.f, 0.f, 0.f};
    float ab[4] = {0.f, 0.f, 0.f, 0.f};
#pragma unroll 8
    for (int f = 0; f < 64; ++f) {
        float wa = W2[f * HID + t];
        float wb = W2[(64 + f) * HID + t];
#pragma unroll
        for (int i = 0; i < 4; ++i) {
            float h = h1s[w * 4 + i][f];   // broadcast ds_read
            aa[i] = fmaf(h, wa, aa[i]);
            ab[i] = fmaf(h, wb, ab[i]);
        }
    }
    float bt = b2[t];
#pragma unroll
    for (int i = 0; i < 4; ++i) {
        C2[(pb + i) * HID + t] = bt + aa[i] - ab[i];
        Y2[(pb + i) * HID + t] = ab[i];
    }
}

// ec2_maxpool: val = relu(C2 + max_k Y2[idx[k]]); block-partial max-pool.
__global__ __launch_bounds__(256) void ec2_maxpool_kernel(const float* __restrict__ C2,
                                                          const float* __restrict__ Y2,
                                                          const int* __restrict__ idx,
                                                          float* __restrict__ gpartial) {
    int t = threadIdx.x & 63;
    int lp = threadIdx.x >> 6;
    int p = blockIdx.x * 4 + lp;
    const int4* ip = (const int4*)(idx + (size_t)p * KNN);
    int4 n0 = ip[0], n1 = ip[1], n2 = ip[2], n3 = ip[3];
    int jj[16] = {n0.x, n0.y, n0.z, n0.w, n1.x, n1.y, n1.z, n1.w,
                  n2.x, n2.y, n2.z, n2.w, n3.x, n3.y, n3.z, n3.w};
    float m = -INFINITY;
#pragma unroll
    for (int k = 0; k < KNN; ++k) {
        m = fmaxf(m, Y2[jj[k] * HID + t]);   // 16 independent gathers
    }
    float val = fmaxf(C2[p * HID + t] + m, 0.f);
    __shared__ float red[4][64];
    red[lp][t] = val;
    __syncthreads();
    if (lp == 0) {
        float g = fmaxf(fmaxf(red[0][t], red[1][t]), fmaxf(red[2][t], red[3][t]));
        gpartial[blockIdx.x * 64 + t] = g;
    }
}

// greduce2: 4096 -> 256 partial rows, fully coalesced, 256 parallel blocks.
__global__ __launch_bounds__(256) void greduce2_kernel(const float* __restrict__ gpartial,
                                                       float* __restrict__ gp2) {
    __shared__ float red[4][64];
    int f = threadIdx.x & 63;
    int w = threadIdx.x >> 6;
    int r0 = blockIdx.x * 16 + w * 4;
    float m = -INFINITY;
#pragma unroll
    for (int r = 0; r < 4; ++r) m = fmaxf(m, gpartial[(r0 + r) * 64 + f]);
    red[w][f] = m;
    __syncthreads();
    if (w == 0)
        gp2[blockIdx.x * 64 + f] =
            fmaxf(fmaxf(red[0][f], red[1][f]), fmaxf(red[2][f], red[3][f]));
}

// tail2: 256 rows -> g[64], then linear head. One block (cheap now).
__global__ __launch_bounds__(256) void tail2_kernel(const float* __restrict__ gp2,
                                                    const float* __restrict__ Wc,
                                                    const float* __restrict__ bc,
                                                    float* __restrict__ out) {
    __shared__ float red[4][64];
    __shared__ float g[64];
    int f = threadIdx.x & 63;
    int w = threadIdx.x >> 6;
    float m = -INFINITY;
    for (int i = w; i < 256; i += 4) m = fmaxf(m, gp2[i * 64 + f]);
    red[w][f] = m;
    __syncthreads();
    if (w == 0) g[f] = fmaxf(fmaxf(red[0][f], red[1][f]), fmaxf(red[2][f], red[3][f]));
    __syncthreads();
    if (threadIdx.x < NCLS) {
        float a = bc[threadIdx.x];
#pragma unroll
        for (int h = 0; h < HID; ++h) a = fmaf(g[h], Wc[h * NCLS + threadIdx.x], a);
        out[threadIdx.x] = a;
    }
}

extern "C" void kernel_launch(void* const* d_in, const int* in_sizes, int n_in,
                              void* d_out, int out_size, void* d_ws, size_t ws_size,
                              hipStream_t stream) {
    const float* pos = (const float*)d_in[0];
    // d_in[1] = batch (all zeros, num_segments=1) -> unused
    const float* W1 = (const float*)d_in[2];
    const float* b1 = (const float*)d_in[3];
    const float* W2 = (const float*)d_in[4];
    const float* b2 = (const float*)d_in[5];
    const float* Wc = (const float*)d_in[6];
    const float* bc = (const float*)d_in[7];
    float* out = (float*)d_out;

    char* ws = (char*)d_ws;
    size_t o = 0;
    auto alloc = [&](size_t bytes) { size_t r = o; o += (bytes + 255) & ~size_t(255); return r; };
    size_t fm = (size_t)NPTS * HID * 4;
    size_t o_pos4 = alloc((size_t)NPTS * 16);
    size_t o_pm2 = alloc((size_t)NPTS * 16);
    size_t o_pm2t = alloc((size_t)(NPTS + TPAD) * 16);
    size_t o_tqg = alloc((size_t)NPTS * 4);
    size_t o_idx = alloc((size_t)NPTS * KNN * 4);
    size_t o_C2 = alloc(fm);
    size_t o_Y2 = alloc(fm);
    size_t o_gp = alloc((size_t)(NPTS / 4) * HID * 4);
    size_t o_gp2 = alloc((size_t)256 * HID * 4);

    float4* pos4 = (float4*)(ws + o_pos4);
    float4* pm2 = (float4*)(ws + o_pm2);
    float4* pm2t = (float4*)(ws + o_pm2t);
    float* tqg = (float*)(ws + o_tqg);
    int* idx = (int*)(ws + o_idx);
    float* C2 = (float*)(ws + o_C2);
    float* Y2 = (float*)(ws + o_Y2);
    float* gp = (float*)(ws + o_gp);
    float* gp2 = (float*)(ws + o_gp2);

    // zero the pm2t prefetch pad (loaded but never consumed)
    hipMemsetAsync(pm2t + NPTS, 0, TPAD * sizeof(float4), stream);

    prep_kernel<<<NPTS / 256, 256, 0, stream>>>(pos, pos4, pm2, pm2t);
    knn_tau_kernel<<<NPTS / (4 * TQW), 256, 0, stream>>>(pos4, pm2t, tqg);
    knn_sel_kernel<<<NPTS / QPB, 256, 0, stream>>>(pos4, pm2, pm2t, tqg, idx);
    ec12_kernel<<<NPTS / 16, 256, 0, stream>>>(pos4, idx, W1, b1, W2, b2, C2, Y2);
    ec2_maxpool_kernel<<<NPTS / 4, 256, 0, stream>>>(C2, Y2, idx, gp);
    greduce2_kernel<<<256, 256, 0, stream>>>(gp, gp2);
    tail2_kernel<<<1, 256, 0, stream>>>(gp2, Wc, bc, out);
}

// Round 5
// 305.279 us; speedup vs baseline: 1.0034x; 1.0034x over previous
//
#include <hip/hip_runtime.h>

#define NPTS 16384
#define KNN 16
#define HID 64
#define NCLS 10

#define WPB 4              // waves per block (knn_sel)
#define QPB 8              // queries per block (knn_sel)
#define SCAP 128           // per-query survivor capacity (block-shared LDS list)
#define GRPQ 32            // candidate groups per wave quarter (knn_sel)
#define NITER 16           // iters per scan of a quarter (2 groups per iter)
#define NGRP (NPTS / 128)  // 128 total pair-groups
#define TQW 4              // queries per wave (knn_tau)
#define TPAD 576           // pm2t pad (kept; wrap makes overrun impossible now)

typedef float v2f __attribute__((ext_vector_type(2)));

// packed distance: D = {d(c0), d(c1)} = Qx*X + Qy*Y + Qz*Z + W  (3 pk_fma)
__device__ __forceinline__ v2f pdist(v2f Qx, v2f Qy, v2f Qz, v2f X, v2f Y, v2f Z, v2f W) {
    return __builtin_elementwise_fma(Qx, X,
            __builtin_elementwise_fma(Qy, Y,
             __builtin_elementwise_fma(Qz, Z, W)));
}

// scalar twin (rescan path) — identical op order => bit-exact vs packed halves
__device__ __forceinline__ float distm2(float qx, float qy, float qz, float4 c) {
    return fmaf(qx, c.x, fmaf(qy, c.y, fmaf(qz, c.z, c.w)));
}

// wave-uniform float -> SGPR
__device__ __forceinline__ float __frfl(float x) {
    return __int_as_float(__builtin_amdgcn_readfirstlane(__float_as_int(x)));
}

// monotone float->u32, packed with index: ascending u64 order == (d asc, j asc)
__device__ __forceinline__ unsigned long long dkey(float v, int j) {
    unsigned u = __float_as_uint(v);
    u = (u & 0x80000000u) ? ~u : (u | 0x80000000u);
    return ((unsigned long long)u << 32) | (unsigned)j;
}

__device__ __forceinline__ unsigned long long shfl_xor_u64(unsigned long long x, int m) {
    unsigned hi = (unsigned)__shfl_xor((int)(x >> 32), m, 64);
    unsigned lo = (unsigned)__shfl_xor((int)(x & 0xffffffffu), m, 64);
    return ((unsigned long long)hi << 32) | lo;
}

// exact wave-wide top-16 (rescan slow path only)
__device__ __forceinline__ void wave_top16_16(unsigned long long (&key)[16], int lane,
                                              int q, int* __restrict__ idx) {
    int outj = 0x7fffffff;
    for (int r = 0; r < 16; ++r) {
        unsigned long long gm = key[0];
#pragma unroll
        for (int s = 1; s < 16; ++s) gm = key[s] < gm ? key[s] : gm;
#pragma unroll
        for (int st = 1; st < 64; st <<= 1) {
            unsigned long long o = shfl_xor_u64(gm, st);
            gm = o < gm ? o : gm;
        }
        if (lane == r) outj = (int)(gm & 0xffffffffu);
#pragma unroll
        for (int s = 0; s < 16; ++s)
            if (key[s] == gm) key[s] = ~0ull;
    }
    if (lane < 16) idx[q * KNN + lane] = outj;
}

// pos (N,3) -> pos4 (x,y,z,|p|^2), pm2 (-2x,-2y,-2z,|p|^2) [rescan path],
// pm2t pair-transposed: group g (64 pairs): [g*128+l]=(x0,x1,y0,y1) of pair g*64+l,
//                                           [g*128+64+l]=(z0,z1,w0,w1)
__global__ void prep_kernel(const float* __restrict__ pos, float4* __restrict__ pos4,
                            float4* __restrict__ pm2, float4* __restrict__ pm2t) {
    int i = blockIdx.x * 256 + threadIdx.x;
    if (i < NPTS) {
        float x = pos[3 * i], y = pos[3 * i + 1], z = pos[3 * i + 2];
        float sq = fmaf(x, x, fmaf(y, y, z * z));
        pos4[i] = make_float4(x, y, z, sq);
        pm2[i] = make_float4(-2.f * x, -2.f * y, -2.f * z, sq);
    }
    if (i < NPTS / 2) {
        int p = i;                       // pair p = candidates 2p, 2p+1
        float x0 = pos[6 * p],     y0 = pos[6 * p + 1], z0 = pos[6 * p + 2];
        float x1 = pos[6 * p + 3], y1 = pos[6 * p + 4], z1 = pos[6 * p + 5];
        float w0 = fmaf(x0, x0, fmaf(y0, y0, z0 * z0));
        float w1 = fmaf(x1, x1, fmaf(y1, y1, z1 * z1));
        int g = p >> 6, l = p & 63;
        pm2t[g * 128 + l]      = make_float4(-2.f * x0, -2.f * x1, -2.f * y0, -2.f * y1);
        pm2t[g * 128 + 64 + l] = make_float4(-2.f * z0, -2.f * z1, w0, w1);
    }
}

// knn_tau: BARRIER-FREE, LDS-FREE tau. One wave owns TQW=4 queries and scans
// all N candidates (packed pairs). ROTATED scan start: each wave begins at a
// different group (mod NGRP) so the machine's address streams decorrelate
// (anti hot-line). tau = max over 16 streams of the stream minimum (streams
// are lane-mod-16 partitions: rotation permutes groups within streams only).
__global__ __launch_bounds__(256) void knn_tau_kernel(const float4* __restrict__ pos4,
                                                      const float4* __restrict__ pm2t,
                                                      float* __restrict__ tqg) {
    int lane = threadIdx.x & 63;
    int w = threadIdx.x >> 6;
    int q0 = (blockIdx.x * 4 + w) * TQW;
    v2f Qx[TQW], Qy[TQW], Qz[TQW];
#pragma unroll
    for (int i = 0; i < TQW; ++i) {
        float4 t4 = pos4[q0 + i];          // wave-uniform
        float ax = __frfl(t4.x), ay = __frfl(t4.y), az = __frfl(t4.z);
        Qx[i] = (v2f){ax, ax}; Qy[i] = (v2f){ay, ay}; Qz[i] = (v2f){az, az};
    }
    const float4* pt = pm2t + lane;
    int start = (((blockIdx.x >> 3) << 2) + w) & (NGRP - 1);   // spread per XCD
    float mn[TQW];
#pragma unroll
    for (int i = 0; i < TQW; ++i) mn[i] = INFINITY;
    {
        int g0 = start, g1 = (start + 1) & (NGRP - 1);
        int g2 = (start + 2) & (NGRP - 1), g3 = (start + 3) & (NGRP - 1);
        float4 aXY0 = pt[g0 * 128], aZW0 = pt[g0 * 128 + 64];
        float4 aXY1 = pt[g1 * 128], aZW1 = pt[g1 * 128 + 64];
        float4 bXY0 = pt[g2 * 128], bZW0 = pt[g2 * 128 + 64];
        float4 bXY1 = pt[g3 * 128], bZW1 = pt[g3 * 128 + 64];
#pragma unroll 2
        for (int t = 0; t < NGRP / 2; ++t) {       // 64 iters, 2 groups each
            v2f X0 = {aXY0.x, aXY0.y}, Y0 = {aXY0.z, aXY0.w};
            v2f Z0 = {aZW0.x, aZW0.y}, W0 = {aZW0.z, aZW0.w};
            v2f X1 = {aXY1.x, aXY1.y}, Y1 = {aXY1.z, aXY1.w};
            v2f Z1 = {aZW1.x, aZW1.y}, W1 = {aZW1.z, aZW1.w};
#pragma unroll
            for (int i = 0; i < TQW; ++i) {
                v2f D0 = pdist(Qx[i], Qy[i], Qz[i], X0, Y0, Z0, W0);
                v2f D1 = pdist(Qx[i], Qy[i], Qz[i], X1, Y1, Z1, W1);
                mn[i] = fminf(mn[i], fminf(D0.x, D0.y));   // v_min3
                mn[i] = fminf(mn[i], fminf(D1.x, D1.y));   // v_min3
            }
            int gp0 = (start + 2 * t + 4) & (NGRP - 1);
            int gp1 = (start + 2 * t + 5) & (NGRP - 1);
            aXY0 = bXY0; aZW0 = bZW0; aXY1 = bXY1; aZW1 = bZW1;
            bXY0 = pt[gp0 * 128]; bZW0 = pt[gp0 * 128 + 64];
            bXY1 = pt[gp1 * 128]; bZW1 = pt[gp1 * 128 + 64];
        }
    }
#pragma unroll
    for (int i = 0; i < TQW; ++i) {
        float m = mn[i];
        m = fminf(m, __shfl_xor(m, 16, 64));   // lane now holds stream-min(lane&15)
        m = fminf(m, __shfl_xor(m, 32, 64));
        m = fmaxf(m, __shfl_xor(m, 1, 64));    // max over the 16 stream minima
        m = fmaxf(m, __shfl_xor(m, 2, 64));
        m = fmaxf(m, __shfl_xor(m, 4, 64));
        m = fmaxf(m, __shfl_xor(m, 8, 64));
        if (lane == 0) tqg[q0 + i] = m;
    }
}

// knn_sel: tau-filtered push + rank-select extraction. Block = 4 waves sharing
// 8 queries; wave w scans its quarter, ROTATED start (anti hot-line).
__global__ __launch_bounds__(256) void knn_sel_kernel(const float4* __restrict__ pos4,
                                                      const float4* __restrict__ pm2,
                                                      const float4* __restrict__ pm2t,
                                                      const float* __restrict__ tqg,
                                                      int* __restrict__ idx) {
    __shared__ unsigned long long keys[QPB][SCAP];   // 8KB
    __shared__ int knt[QPB];
    int tid = threadIdx.x;
    int lane = tid & 63;
    int w = tid >> 6;
    int qb = blockIdx.x * QPB;
    v2f Qx[QPB], Qy[QPB], Qz[QPB];
    float tq[QPB];
#pragma unroll
    for (int i = 0; i < QPB; ++i) {
        float4 t4 = pos4[qb + i];          // wave-uniform (needed for rescan)
        float ax = __frfl(t4.x), ay = __frfl(t4.y), az = __frfl(t4.z);
        Qx[i] = (v2f){ax, ax}; Qy[i] = (v2f){ay, ay}; Qz[i] = (v2f){az, az};
        tq[i] = __frfl(tqg[qb + i]);
    }
    if (tid < QPB) knt[tid] = 0;
    __syncthreads();   // knt visible

    const float4* ptq = pm2t + (size_t)w * (GRPQ * 128) + lane;
    int pb0 = w * (GRPQ * 64);             // pair-index base of this quarter
    int start = (blockIdx.x >> 3) & (GRPQ - 1);   // resident set covers all starts
    {
        int g0 = start, g1 = (start + 1) & (GRPQ - 1);
        int g2 = (start + 2) & (GRPQ - 1), g3 = (start + 3) & (GRPQ - 1);
        float4 aXY0 = ptq[g0 * 128], aZW0 = ptq[g0 * 128 + 64];
        float4 aXY1 = ptq[g1 * 128], aZW1 = ptq[g1 * 128 + 64];
        float4 bXY0 = ptq[g2 * 128], bZW0 = ptq[g2 * 128 + 64];
        float4 bXY1 = ptq[g3 * 128], bZW1 = ptq[g3 * 128 + 64];
#pragma unroll 2
        for (int t = 0; t < NITER; ++t) {
            v2f X0 = {aXY0.x, aXY0.y}, Y0 = {aXY0.z, aXY0.w};
            v2f Z0 = {aZW0.x, aZW0.y}, W0 = {aZW0.z, aZW0.w};
            v2f X1 = {aXY1.x, aXY1.y}, Y1 = {aXY1.z, aXY1.w};
            v2f Z1 = {aZW1.x, aZW1.y}, W1 = {aZW1.z, aZW1.w};
            int ga = (start + 2 * t) & (GRPQ - 1);
            int gb = (start + 2 * t + 1) & (GRPQ - 1);
            int j00 = 2 * (pb0 + ga * 64 + lane);   // slot0: j00, j00+1
            int j10 = 2 * (pb0 + gb * 64 + lane);   // slot1: j10, j10+1
#pragma unroll
            for (int i = 0; i < QPB; ++i) {
                v2f D0 = pdist(Qx[i], Qy[i], Qz[i], X0, Y0, Z0, W0);
                v2f D1 = pdist(Qx[i], Qy[i], Qz[i], X1, Y1, Z1, W1);
                float m01 = fminf(fminf(D0.x, D0.y), fminf(D1.x, D1.y));
                if (__any(m01 <= tq[i])) {             // vccz skip most iters
                    if (D0.x <= tq[i]) { int s = atomicAdd(&knt[i], 1); if (s < SCAP) keys[i][s] = dkey(D0.x, j00); }
                    if (D0.y <= tq[i]) { int s = atomicAdd(&knt[i], 1); if (s < SCAP) keys[i][s] = dkey(D0.y, j00 + 1); }
                    if (D1.x <= tq[i]) { int s = atomicAdd(&knt[i], 1); if (s < SCAP) keys[i][s] = dkey(D1.x, j10); }
                    if (D1.y <= tq[i]) { int s = atomicAdd(&knt[i], 1); if (s < SCAP) keys[i][s] = dkey(D1.y, j10 + 1); }
                }
            }
            int gp0 = (start + 2 * t + 4) & (GRPQ - 1);
            int gp1 = (start + 2 * t + 5) & (GRPQ - 1);
            aXY0 = bXY0; aZW0 = bZW0; aXY1 = bXY1; aZW1 = bZW1;
            bXY0 = ptq[gp0 * 128]; bZW0 = ptq[gp0 * 128 + 64];
            bXY1 = ptq[gp1 * 128]; bZW1 = ptq[gp1 * 128 + 64];
        }
    }
    __syncthreads();   // all pushes visible

    // ---- Extraction: wave w handles queries 2w, 2w+1; 8-wide rank loop ----
#pragma unroll
    for (int e = 0; e < 2; ++e) {
        int qi = w * 2 + e;
        int q = qb + qi;
        int ntot = knt[qi];
        if (ntot >= KNN && ntot <= SCAP) {
            unsigned long long k0 = (lane < ntot) ? keys[qi][lane] : ~0ull;
            unsigned long long k1 = (lane + 64 < ntot) ? keys[qi][lane + 64] : ~0ull;
            int r0 = 0, r1 = 0;
            int t = 0;
            for (; t + 8 <= ntot; t += 8) {             // 8 independent ds_reads
                unsigned long long a0 = keys[qi][t + 0], a1 = keys[qi][t + 1];
                unsigned long long a2 = keys[qi][t + 2], a3 = keys[qi][t + 3];
                unsigned long long a4 = keys[qi][t + 4], a5 = keys[qi][t + 5];
                unsigned long long a6 = keys[qi][t + 6], a7 = keys[qi][t + 7];
                r0 += (int)(a0 < k0) + (int)(a1 < k0) + (int)(a2 < k0) + (int)(a3 < k0)
                    + (int)(a4 < k0) + (int)(a5 < k0) + (int)(a6 < k0) + (int)(a7 < k0);
                r1 += (int)(a0 < k1) + (int)(a1 < k1) + (int)(a2 < k1) + (int)(a3 < k1)
                    + (int)(a4 < k1) + (int)(a5 < k1) + (int)(a6 < k1) + (int)(a7 < k1);
            }
            for (; t < ntot; ++t) {
                unsigned long long k = keys[qi][t];
                r0 += (int)(k < k0);
                r1 += (int)(k < k1);
            }
            if (lane < ntot && r0 < KNN) idx[q * KNN + r0] = (int)(k0 & 0xffffffffu);
            if (lane + 64 < ntot && r1 < KNN) idx[q * KNN + r1] = (int)(k1 & 0xffffffffu);
        } else {
            // rescan: overflow -> tau-filtered (tau >= d16 guaranteed);
            // underflow (defensive) -> unfiltered top-16
            float tqq = (ntot > SCAP) ? tq[qi] : INFINITY;
            float ax = Qx[qi].x, ay = Qy[qi].x, az = Qz[qi].x;
            unsigned long long key[16];
#pragma unroll
            for (int u = 0; u < 16; ++u) key[u] = ~0ull;
            for (int j = lane; j < NPTS; j += 64) {
                float v = distm2(ax, ay, az, pm2[j]);
                unsigned long long k = dkey(v, j);
                if (v <= tqq && k < key[15]) {
#pragma unroll
                    for (int s = 0; s < 16; ++s) {
                        unsigned long long a = k < key[s] ? k : key[s];
                        unsigned long long b = k < key[s] ? key[s] : k;
                        key[s] = a;
                        k = b;
                    }
                }
            }
            wave_top16_16(key, lane, q, idx);
        }
    }
}

// FUSED EdgeConv1 + ec2_pre (both pointwise in p; h1 never touches global).
__global__ __launch_bounds__(256) void ec12_kernel(const float4* __restrict__ pos4,
                                                   const int* __restrict__ idx,
                                                   const float* __restrict__ W1,
                                                   const float* __restrict__ b1,
                                                   const float* __restrict__ W2,
                                                   const float* __restrict__ b2,
                                                   float* __restrict__ C2,
                                                   float* __restrict__ Y2) {
    __shared__ float h1s[16][64];    // 4KB, [w*4+i][t], wave-private slices
    int t = threadIdx.x & 63;
    int w = threadIdx.x >> 6;
    int pb = blockIdx.x * 16 + w * 4;
    float w0 = W1[0 * HID + t], w1 = W1[1 * HID + t], w2 = W1[2 * HID + t];
    float v0 = W1[3 * HID + t], v1 = W1[4 * HID + t], v2 = W1[5 * HID + t];
    float bt1 = b1[t];
#pragma unroll
    for (int i = 0; i < 4; ++i) {
        int p = pb + i;
        float4 xi = pos4[p];
        float C = bt1 + xi.x * (w0 - v0) + xi.y * (w1 - v1) + xi.z * (w2 - v2);
        const int4* ip = (const int4*)(idx + (size_t)p * KNN);
        int4 n0 = ip[0], n1 = ip[1], n2 = ip[2], n3 = ip[3];   // 4 parallel loads
        int jj[16] = {n0.x, n0.y, n0.z, n0.w, n1.x, n1.y, n1.z, n1.w,
                      n2.x, n2.y, n2.z, n2.w, n3.x, n3.y, n3.z, n3.w};
        float m = -INFINITY;
#pragma unroll
        for (int k = 0; k < KNN; ++k) {
            float4 xj = pos4[jj[k]];      // 16 mutually-independent uniform loads
            m = fmaxf(m, fmaf(xj.x, v0, fmaf(xj.y, v1, xj.z * v2)));
        }
        h1s[w * 4 + i][t] = fmaxf(C + m, 0.f);
    }
    __syncthreads();
    float aa[4] = {0.f, 0.f, 0.f, 0.f};
    float ab[4] = {0.f, 0.f, 0.f, 0.f};
#pragma unroll 8
    for (int f = 0; f < 64; ++f) {
        float wa = W2[f * HID + t];
        float wb = W2[(64 + f) * HID + t];
#pragma unroll
        for (int i = 0; i < 4; ++i) {
            float h = h1s[w * 4 + i][f];   // broadcast ds_read
            aa[i] = fmaf(h, wa, aa[i]);
            ab[i] = fmaf(h, wb, ab[i]);
        }
    }
    float bt = b2[t];
#pragma unroll
    for (int i = 0; i < 4; ++i) {
        C2[(pb + i) * HID + t] = bt + aa[i] - ab[i];
        Y2[(pb + i) * HID + t] = ab[i];
    }
}

// ec2_maxpool: val = relu(C2 + max_k Y2[idx[k]]); block-partial max-pool.
__global__ __launch_bounds__(256) void ec2_maxpool_kernel(const float* __restrict__ C2,
                                                          const float* __restrict__ Y2,
                                                          const int* __restrict__ idx,
                                                          float* __restrict__ gpartial) {
    int t = threadIdx.x & 63;
    int lp = threadIdx.x >> 6;
    int p = blockIdx.x * 4 + lp;
    const int4* ip = (const int4*)(idx + (size_t)p * KNN);
    int4 n0 = ip[0], n1 = ip[1], n2 = ip[2], n3 = ip[3];
    int jj[16] = {n0.x, n0.y, n0.z, n0.w, n1.x, n1.y, n1.z, n1.w,
                  n2.x, n2.y, n2.z, n2.w, n3.x, n3.y, n3.z, n3.w};
    float m = -INFINITY;
#pragma unroll
    for (int k = 0; k < KNN; ++k) {
        m = fmaxf(m, Y2[jj[k] * HID + t]);   // 16 independent gathers
    }
    float val = fmaxf(C2[p * HID + t] + m, 0.f);
    __shared__ float red[4][64];
    red[lp][t] = val;
    __syncthreads();
    if (lp == 0) {
        float g = fmaxf(fmaxf(red[0][t], red[1][t]), fmaxf(red[2][t], red[3][t]));
        gpartial[blockIdx.x * 64 + t] = g;
    }
}

// greduce2: 4096 -> 256 partial rows, fully coalesced, 256 parallel blocks.
__global__ __launch_bounds__(256) void greduce2_kernel(const float* __restrict__ gpartial,
                                                       float* __restrict__ gp2) {
    __shared__ float red[4][64];
    int f = threadIdx.x & 63;
    int w = threadIdx.x >> 6;
    int r0 = blockIdx.x * 16 + w * 4;
    float m = -INFINITY;
#pragma unroll
    for (int r = 0; r < 4; ++r) m = fmaxf(m, gpartial[(r0 + r) * 64 + f]);
    red[w][f] = m;
    __syncthreads();
    if (w == 0)
        gp2[blockIdx.x * 64 + f] =
            fmaxf(fmaxf(red[0][f], red[1][f]), fmaxf(red[2][f], red[3][f]));
}

// tail2: 256 rows -> g[64], then linear head. One block (cheap now).
__global__ __launch_bounds__(256) void tail2_kernel(const float* __restrict__ gp2,
                                                    const float* __restrict__ Wc,
                                                    const float* __restrict__ bc,
                                                    float* __restrict__ out) {
    __shared__ float red[4][64];
    __shared__ float g[64];
    int f = threadIdx.x & 63;
    int w = threadIdx.x >> 6;
    float m = -INFINITY;
    for (int i = w; i < 256; i += 4) m = fmaxf(m, gp2[i * 64 + f]);
    red[w][f] = m;
    __syncthreads();
    if (w == 0) g[f] = fmaxf(fmaxf(red[0][f], red[1][f]), fmaxf(red[2][f], red[3][f]));
    __syncthreads();
    if (threadIdx.x < NCLS) {
        float a = bc[threadIdx.x];
#pragma unroll
        for (int h = 0; h < HID; ++h) a = fmaf(g[h], Wc[h * NCLS + threadIdx.x], a);
        out[threadIdx.x] = a;
    }
}

extern "C" void kernel_launch(void* const* d_in, const int* in_sizes, int n_in,
                              void* d_out, int out_size, void* d_ws, size_t ws_size,
                              hipStream_t stream) {
    const float* pos = (const float*)d_in[0];
    // d_in[1] = batch (all zeros, num_segments=1) -> unused
    const float* W1 = (const float*)d_in[2];
    const float* b1 = (const float*)d_in[3];
    const float* W2 = (const float*)d_in[4];
    const float* b2 = (const float*)d_in[5];
    const float* Wc = (const float*)d_in[6];
    const float* bc = (const float*)d_in[7];
    float* out = (float*)d_out;

    char* ws = (char*)d_ws;
    size_t o = 0;
    auto alloc = [&](size_t bytes) { size_t r = o; o += (bytes + 255) & ~size_t(255); return r; };
    size_t fm = (size_t)NPTS * HID * 4;
    size_t o_pos4 = alloc((size_t)NPTS * 16);
    size_t o_pm2 = alloc((size_t)NPTS * 16);
    size_t o_pm2t = alloc((size_t)(NPTS + TPAD) * 16);
    size_t o_tqg = alloc((size_t)NPTS * 4);
    size_t o_idx = alloc((size_t)NPTS * KNN * 4);
    size_t o_C2 = alloc(fm);
    size_t o_Y2 = alloc(fm);
    size_t o_gp = alloc((size_t)(NPTS / 4) * HID * 4);
    size_t o_gp2 = alloc((size_t)256 * HID * 4);

    float4* pos4 = (float4*)(ws + o_pos4);
    float4* pm2 = (float4*)(ws + o_pm2);
    float4* pm2t = (float4*)(ws + o_pm2t);
    float* tqg = (float*)(ws + o_tqg);
    int* idx = (int*)(ws + o_idx);
    float* C2 = (float*)(ws + o_C2);
    float* Y2 = (float*)(ws + o_Y2);
    float* gp = (float*)(ws + o_gp);
    float* gp2 = (float*)(ws + o_gp2);

    prep_kernel<<<NPTS / 256, 256, 0, stream>>>(pos, pos4, pm2, pm2t);
    knn_tau_kernel<<<NPTS / (4 * TQW), 256, 0, stream>>>(pos4, pm2t, tqg);
    knn_sel_kernel<<<NPTS / QPB, 256, 0, stream>>>(pos4, pm2, pm2t, tqg, idx);
    ec12_kernel<<<NPTS / 16, 256, 0, stream>>>(pos4, idx, W1, b1, W2, b2, C2, Y2);
    ec2_maxpool_kernel<<<NPTS / 4, 256, 0, stream>>>(C2, Y2, idx, gp);
    greduce2_kernel<<<256, 256, 0, stream>>>(gp, gp2);
    tail2_kernel<<<1, 256, 0, stream>>>(gp2, Wc, bc, out);
}